// Round 4
// baseline (806.924 us; speedup 1.0000x reference)
//
#include <hip/hip_runtime.h>
#include <hip/hip_bf16.h>
#include <stdint.h>

#define NN 50000
#define NE 800000
#define EPS 1e-5f

// CSR bucket params
#define KB 196       // buckets = ceil(NN / NPB)
#define SH 8         // bucket = dst >> SH
#define NPB 256      // nodes per bucket
#define RCAP 4500    // slots per bucket (mean 4082, +6.6 sigma)
#define PT2 2048     // edges per DS-partition block

typedef __attribute__((ext_vector_type(8))) short bf16x8;
typedef __attribute__((ext_vector_type(4))) float floatx4;

static __device__ __forceinline__ float bf2f(unsigned int u){
  union { unsigned int i; float f; } c; c.i = u << 16; return c.f;
}
static __device__ __forceinline__ unsigned short f2bf(float f){
  union { float f; unsigned int i; } c; c.f = f;
  unsigned int x = c.i;
  return (unsigned short)((x + 0x7fffu + ((x >> 16) & 1u)) >> 16);
}

// fused f32 -> bf16 converter for x + the 6 GEMM weight matrices;
// also zeros bucket cursors and the ea scatter-sum accumulator
#define CVT_X   3200000
#define CVT_W1  3212288
#define CVT_WL2 3228672
#define CVT_WR2 3245056
#define CVT_WL3 3261440
#define CVT_WR3 3277824
#define CVT_END 3290112
__global__ void k_cvt_all(const float* __restrict__ x,  const float* __restrict__ W1,
                          const float* __restrict__ Wl2, const float* __restrict__ Wr2,
                          const float* __restrict__ Wl3, const float* __restrict__ Wr3,
                          const float* __restrict__ W4,
                          unsigned short* __restrict__ xb,  unsigned short* __restrict__ W1b,
                          unsigned short* __restrict__ Wl2b, unsigned short* __restrict__ Wr2b,
                          unsigned short* __restrict__ Wl3b, unsigned short* __restrict__ Wr3b,
                          unsigned short* __restrict__ W4b, int* __restrict__ gcur,
                          float* __restrict__ aggE){
  int i = blockIdx.x * 256 + threadIdx.x;
  if(i >= CVT_END) return;
  if(i < 3 * KB) gcur[i] = 0;
  if(i < NN * 32) aggE[i] = 0.f;
  if(i < CVT_X)        xb[i] = f2bf(x[i]);
  else if(i < CVT_W1)  W1b[i - CVT_X]    = f2bf(W1[i - CVT_X]);
  else if(i < CVT_WL2) Wl2b[i - CVT_W1]  = f2bf(Wl2[i - CVT_W1]);
  else if(i < CVT_WR2) Wr2b[i - CVT_WL2] = f2bf(Wr2[i - CVT_WL2]);
  else if(i < CVT_WL3) Wl3b[i - CVT_WR2] = f2bf(Wl3[i - CVT_WR2]);
  else if(i < CVT_WR3) Wr3b[i - CVT_WL3] = f2bf(Wr3[i - CVT_WL3]);
  else                 W4b[i - CVT_WR3]  = f2bf(W4[i - CVT_WR3]);
}

// ---- streaming ea segment-sum: coalesced edge-order read, atomic scatter into
// aggE[dst][32] f32. Replaces the random 128B ea gather that was HBM-bound at
// ~1.3 TB/s (random) with a sequential stream + 25.6M low-contention atomics. ----
__global__ void k_sumEA(const int* __restrict__ ei, const float* __restrict__ ea,
                        float* __restrict__ aggE){
  int t = blockIdx.x * 256 + threadIdx.x;
  int e = t >> 3, li = t & 7;
  if(e >= NE) return;
  int dst = ei[NE + e];
  float4 v = *(const float4*)(ea + (size_t)e * 32 + li * 4);
  float* p = aggE + (size_t)dst * 32 + li * 4;
  atomicAdd(p + 0, v.x);
  atomicAdd(p + 1, v.y);
  atomicAdd(p + 2, v.z);
  atomicAdd(p + 3, v.w);
}

// ---- DS-only partition (all 3 layers; parallel scan) ----
__global__ void k_part(const int* __restrict__ ei, int* __restrict__ gcur, int2* __restrict__ rec){
  __shared__ int2 stage[PT2];
  __shared__ int hist[KB], ex[KB], cur[KB], gbase[KB];
  __shared__ int part[256];
  __shared__ int tot;
  int tid = threadIdx.x;
  int tile = blockIdx.x * PT2;
  for(int i = tid; i < KB; i += 256) hist[i] = 0;
  __syncthreads();
  int dst[8], src[8];
  #pragma unroll
  for(int j = 0; j < 8; j++){
    int e = tile + j * 256 + tid;
    if(e < NE){ src[j] = ei[e]; dst[j] = ei[NE + e]; atomicAdd(&hist[dst[j] >> SH], 1); }
    else dst[j] = -1;
  }
  __syncthreads();
  int c0 = (tid < KB) ? hist[tid] : 0;
  part[tid] = c0;
  __syncthreads();
  for(int d = 1; d < 256; d <<= 1){
    int v = (tid >= d) ? part[tid - d] : 0;
    __syncthreads();
    part[tid] += v;
    __syncthreads();
  }
  if(tid < KB){
    int e = part[tid] - c0;
    ex[tid] = e; cur[tid] = e;
    gbase[tid] = atomicAdd(&gcur[tid], c0);
  }
  if(tid == 255) tot = part[255];
  __syncthreads();
  #pragma unroll
  for(int j = 0; j < 8; j++){
    if(dst[j] >= 0){
      int b = dst[j] >> SH;
      int s = atomicAdd(&cur[b], 1);
      stage[s] = make_int2(dst[j], src[j]);
    }
  }
  __syncthreads();
  for(int s = tid; s < tot; s += 256){
    int2 r = stage[s];
    int b = r.x >> SH;
    rec[b * RCAP + gbase[b] + (s - ex[b])] = r;
  }
}

// ---- per-bucket CSR build: int adj ----
__global__ void k_build(const int2* __restrict__ rec, const int* __restrict__ gcnt,
                        int* __restrict__ adj, int* __restrict__ rowbeg, int* __restrict__ deg){
  __shared__ int cnt[NPB], cur2[NPB];
  __shared__ int part[256];
  int b = blockIdx.x, tid = threadIdx.x;
  int n0 = b << SH;
  int nr = gcnt[b];
  const int2* r = rec + b * RCAP;
  cnt[tid] = 0;
  __syncthreads();
  for(int k = tid; k < nr; k += 256) atomicAdd(&cnt[r[k].x - n0], 1);
  __syncthreads();
  int c0 = cnt[tid];
  part[tid] = c0;
  __syncthreads();
  for(int d = 1; d < 256; d <<= 1){
    int v = (tid >= d) ? part[tid - d] : 0;
    __syncthreads();
    part[tid] += v;
    __syncthreads();
  }
  int base = part[tid] - c0;
  cur2[tid] = base;
  __syncthreads();
  int n = n0 + tid;
  if(n < NN){ rowbeg[n] = b * RCAP + base; deg[n] = c0; }
  for(int k = tid; k < nr; k += 256){
    int2 q = r[k];
    int p = atomicAdd(&cur2[q.x - n0], 1);
    adj[b * RCAP + p] = q.y;
  }
}

// ---- L0 aggregation, x-only: wave per node, 8 lanes/edge x 16B = one 128B xb row,
// 8 edges/iter x 2 unroll. ea-part comes from the precomputed aggE f32 sums
// (sequential 128B read per node) fused into the same agg-row write. ----
__global__ void k_aggXE(const int* __restrict__ rowbeg, const int* __restrict__ deg,
                        const int* __restrict__ adj,
                        const unsigned short* __restrict__ xb, const float* __restrict__ aggE,
                        unsigned short* __restrict__ agg){
  int w = (blockIdx.x * blockDim.x + threadIdx.x) >> 6;
  int lane = threadIdx.x & 63;
  if(w >= NN) return;
  int sub = lane >> 3, li = lane & 7;
  int r0 = rowbeg[w], dg = deg[w], r1 = r0 + dg;
  float acc[8] = {0.f,0.f,0.f,0.f,0.f,0.f,0.f,0.f};
  for(int k = r0; k < r1; k += 16){
    int e0 = k + sub, e1 = k + 8 + sub;
    int i0 = e0 < r1 ? e0 : r1 - 1;
    int i1 = e1 < r1 ? e1 : r1 - 1;
    float m0 = e0 < r1 ? 1.f : 0.f;
    float m1 = e1 < r1 ? 1.f : 0.f;
    int s0 = adj[i0], s1 = adj[i1];
    uint4 v0 = *(const uint4*)(xb + (size_t)s0 * 64 + li * 8);
    uint4 v1 = *(const uint4*)(xb + (size_t)s1 * 64 + li * 8);
    acc[0] += m0 * bf2f(v0.x & 0xffffu); acc[1] += m0 * bf2f(v0.x >> 16);
    acc[2] += m0 * bf2f(v0.y & 0xffffu); acc[3] += m0 * bf2f(v0.y >> 16);
    acc[4] += m0 * bf2f(v0.z & 0xffffu); acc[5] += m0 * bf2f(v0.z >> 16);
    acc[6] += m0 * bf2f(v0.w & 0xffffu); acc[7] += m0 * bf2f(v0.w >> 16);
    acc[0] += m1 * bf2f(v1.x & 0xffffu); acc[1] += m1 * bf2f(v1.x >> 16);
    acc[2] += m1 * bf2f(v1.y & 0xffffu); acc[3] += m1 * bf2f(v1.y >> 16);
    acc[4] += m1 * bf2f(v1.z & 0xffffu); acc[5] += m1 * bf2f(v1.z >> 16);
    acc[6] += m1 * bf2f(v1.w & 0xffffu); acc[7] += m1 * bf2f(v1.w >> 16);
  }
  #pragma unroll
  for(int d = 8; d < 64; d <<= 1){
    #pragma unroll
    for(int i = 0; i < 8; i++) acc[i] += __shfl_xor(acc[i], d, 64);
  }
  float inv = 1.0f / (float)(dg > 0 ? dg : 1);
  if(lane < 8){
    unsigned int q0 = (unsigned int)f2bf(acc[0]*inv) | ((unsigned int)f2bf(acc[1]*inv) << 16);
    unsigned int q1 = (unsigned int)f2bf(acc[2]*inv) | ((unsigned int)f2bf(acc[3]*inv) << 16);
    unsigned int q2 = (unsigned int)f2bf(acc[4]*inv) | ((unsigned int)f2bf(acc[5]*inv) << 16);
    unsigned int q3 = (unsigned int)f2bf(acc[6]*inv) | ((unsigned int)f2bf(acc[7]*inv) << 16);
    *(uint4*)(agg + (size_t)w * 96 + lane * 8) = make_uint4(q0, q1, q2, q3);
  } else if(lane < 16){
    int j = lane - 8;
    float4 s = *(const float4*)(aggE + (size_t)w * 32 + j * 4);
    unsigned int q0 = (unsigned int)f2bf(s.x*inv) | ((unsigned int)f2bf(s.y*inv) << 16);
    unsigned int q1 = (unsigned int)f2bf(s.z*inv) | ((unsigned int)f2bf(s.w*inv) << 16);
    *(uint2*)(agg + (size_t)w * 96 + 64 + j * 4) = make_uint2(q0, q1);
  }
}

// ---- h aggregation: wave per node; 16 lanes/edge, 16 edges (4 gathers) in flight ----
__global__ void k_aggH(const int* __restrict__ rowbeg, const int* __restrict__ deg,
                       const int* __restrict__ adj,
                       const unsigned short* __restrict__ h, unsigned short* __restrict__ agg){
  int w = (blockIdx.x * blockDim.x + threadIdx.x) >> 6;
  int lane = threadIdx.x & 63;
  if(w >= NN) return;
  int sub = lane >> 4, li = lane & 15;
  int r0 = rowbeg[w], dg = deg[w], r1 = r0 + dg;
  float acc[8] = {0.f,0.f,0.f,0.f,0.f,0.f,0.f,0.f};
  for(int k = r0; k < r1; k += 16){
    uint4 v[4]; float msk[4];
    #pragma unroll
    for(int u = 0; u < 4; u++){
      int e = k + u * 4 + sub;
      int i = e < r1 ? e : r1 - 1;
      msk[u] = e < r1 ? 1.f : 0.f;
      int s = adj[i];
      v[u] = *(const uint4*)(h + (size_t)s * 128 + li * 8);
    }
    #pragma unroll
    for(int u = 0; u < 4; u++){
      acc[0] += msk[u] * bf2f(v[u].x & 0xffffu); acc[1] += msk[u] * bf2f(v[u].x >> 16);
      acc[2] += msk[u] * bf2f(v[u].y & 0xffffu); acc[3] += msk[u] * bf2f(v[u].y >> 16);
      acc[4] += msk[u] * bf2f(v[u].z & 0xffffu); acc[5] += msk[u] * bf2f(v[u].z >> 16);
      acc[6] += msk[u] * bf2f(v[u].w & 0xffffu); acc[7] += msk[u] * bf2f(v[u].w >> 16);
    }
  }
  #pragma unroll
  for(int d = 16; d < 64; d <<= 1){
    #pragma unroll
    for(int i = 0; i < 8; i++) acc[i] += __shfl_xor(acc[i], d, 64);
  }
  if(sub == 0){
    float inv = 1.0f / (float)(dg > 0 ? dg : 1);
    unsigned int p0 = (unsigned int)f2bf(acc[0]*inv) | ((unsigned int)f2bf(acc[1]*inv) << 16);
    unsigned int p1 = (unsigned int)f2bf(acc[2]*inv) | ((unsigned int)f2bf(acc[3]*inv) << 16);
    unsigned int p2 = (unsigned int)f2bf(acc[4]*inv) | ((unsigned int)f2bf(acc[5]*inv) << 16);
    unsigned int p3 = (unsigned int)f2bf(acc[6]*inv) | ((unsigned int)f2bf(acc[7]*inv) << 16);
    *(uint4*)(agg + (size_t)w * 128 + li * 8) = make_uint4(p0, p1, p2, p3);
  }
}

// conv1 dense part: h1 = relu(bn(relu(mask_deg(agg @ W1^T + b1))))
__global__ void k_lin1(const unsigned short* __restrict__ agg, const unsigned short* __restrict__ W1,
                       const float* __restrict__ b1,
                       const float* __restrict__ g1, const float* __restrict__ be1,
                       const float* __restrict__ m1, const float* __restrict__ v1,
                       const int* __restrict__ deg, unsigned short* __restrict__ h1){
  int wave = (blockIdx.x * blockDim.x + threadIdx.x) >> 6;
  int lane = threadIdx.x & 63;
  int mt = wave >> 3, nt = wave & 7;
  if(mt >= 3125) return;
  int node0 = mt * 16;
  int col = lane & 15, quad = lane >> 4;
  int o = nt * 16 + col;
  int arow = node0 + col;
  floatx4 acc = {0.f, 0.f, 0.f, 0.f};
  #pragma unroll
  for(int kc = 0; kc < 3; kc++){
    bf16x8 a = *(const bf16x8*)(agg + arow * 96 + kc * 32 + quad * 8);
    bf16x8 b = *(const bf16x8*)(W1 + o * 96 + kc * 32 + quad * 8);
    acc = __builtin_amdgcn_mfma_f32_16x16x32_bf16(a, b, acc, 0, 0, 0);
  }
  float bb = b1[o];
  float sc = g1[o] * rsqrtf(v1[o] + EPS);
  float mv = m1[o], bev = be1[o];
  #pragma unroll
  for(int r = 0; r < 4; r++){
    int node = node0 + quad * 4 + r;
    float pre = (deg[node] > 0) ? (acc[r] + bb) : 0.0f;   // ref: empty segment -> mean 0, bias never added
    float t = fmaxf(pre, 0.f);
    float bn = sc * (t - mv) + bev;
    h1[node * 128 + o] = f2bf(fmaxf(bn, 0.f));
  }
}

// SAGE: hout = relu(bn(agg @ Wl^T + bl + hin @ Wr^T))
__global__ void k_sage(const unsigned short* __restrict__ agg, const unsigned short* __restrict__ hin,
                       const unsigned short* __restrict__ Wl, const float* __restrict__ bl,
                       const unsigned short* __restrict__ Wr,
                       const float* __restrict__ g, const float* __restrict__ be,
                       const float* __restrict__ m, const float* __restrict__ v,
                       unsigned short* __restrict__ hout){
  int wave = (blockIdx.x * blockDim.x + threadIdx.x) >> 6;
  int lane = threadIdx.x & 63;
  int mt = wave >> 3, nt = wave & 7;
  if(mt >= 3125) return;
  int node0 = mt * 16;
  int col = lane & 15, quad = lane >> 4;
  int o = nt * 16 + col;
  int arow = node0 + col;
  floatx4 acc = {0.f, 0.f, 0.f, 0.f};
  #pragma unroll
  for(int kc = 0; kc < 4; kc++){
    bf16x8 a = *(const bf16x8*)(agg + arow * 128 + kc * 32 + quad * 8);
    bf16x8 b = *(const bf16x8*)(Wl + o * 128 + kc * 32 + quad * 8);
    acc = __builtin_amdgcn_mfma_f32_16x16x32_bf16(a, b, acc, 0, 0, 0);
  }
  #pragma unroll
  for(int kc = 0; kc < 4; kc++){
    bf16x8 a = *(const bf16x8*)(hin + arow * 128 + kc * 32 + quad * 8);
    bf16x8 b = *(const bf16x8*)(Wr + o * 128 + kc * 32 + quad * 8);
    acc = __builtin_amdgcn_mfma_f32_16x16x32_bf16(a, b, acc, 0, 0, 0);
  }
  float blv = bl[o];
  float sc = g[o] * rsqrtf(v[o] + EPS);
  float mv = m[o], bev = be[o];
  #pragma unroll
  for(int r = 0; r < 4; r++){
    int node = node0 + quad * 4 + r;
    float pre = acc[r] + blv;
    float bn = sc * (pre - mv) + bev;
    hout[node * 128 + o] = f2bf(fmaxf(bn, 0.f));
  }
}

// readout: z = relu([h3 | x] @ W4^T + b4) (64), out = z @ W5^T + b5  (f32 out)
__global__ void k_readout(const unsigned short* __restrict__ h3, const unsigned short* __restrict__ xb,
                          const unsigned short* __restrict__ W4, const float* __restrict__ b4,
                          const float* __restrict__ W5, const float* __restrict__ b5,
                          float* __restrict__ out){
  int wave = (blockIdx.x * blockDim.x + threadIdx.x) >> 6;
  int lane = threadIdx.x & 63;
  if(wave >= 3125) return;
  int node0 = wave * 16;
  int col = lane & 15, quad = lane >> 4;
  int arow = node0 + col;
  float partial[4] = {0.f, 0.f, 0.f, 0.f};
  #pragma unroll
  for(int nt = 0; nt < 4; nt++){
    int o = nt * 16 + col;
    floatx4 acc = {0.f, 0.f, 0.f, 0.f};
    #pragma unroll
    for(int kc = 0; kc < 4; kc++){
      bf16x8 a = *(const bf16x8*)(h3 + arow * 128 + kc * 32 + quad * 8);
      bf16x8 b = *(const bf16x8*)(W4 + o * 192 + kc * 32 + quad * 8);
      acc = __builtin_amdgcn_mfma_f32_16x16x32_bf16(a, b, acc, 0, 0, 0);
    }
    #pragma unroll
    for(int kc = 0; kc < 2; kc++){
      bf16x8 a = *(const bf16x8*)(xb + arow * 64 + kc * 32 + quad * 8);
      bf16x8 b = *(const bf16x8*)(W4 + o * 192 + 128 + kc * 32 + quad * 8);
      acc = __builtin_amdgcn_mfma_f32_16x16x32_bf16(a, b, acc, 0, 0, 0);
    }
    float bb = b4[o];
    float w5 = W5[o];
    #pragma unroll
    for(int r = 0; r < 4; r++)
      partial[r] += fmaxf(acc[r] + bb, 0.f) * w5;
  }
  #pragma unroll
  for(int d = 1; d < 16; d <<= 1){
    #pragma unroll
    for(int r = 0; r < 4; r++)
      partial[r] += __shfl_xor(partial[r], d, 64);
  }
  if(col == 0){
    float b5f = b5[0];
    #pragma unroll
    for(int r = 0; r < 4; r++)
      out[node0 + quad * 4 + r] = partial[r] + b5f;
  }
}

extern "C" void kernel_launch(void* const* d_in, const int* in_sizes, int n_in,
                              void* d_out, int out_size, void* d_ws, size_t ws_size,
                              hipStream_t stream) {
  const float* x   = (const float*)d_in[0];
  const int* ei0   = (const int*)d_in[1];
  const int* ei1   = (const int*)d_in[2];
  const int* ei2   = (const int*)d_in[3];
  const float* ea  = (const float*)d_in[4];
  const float* W1  = (const float*)d_in[5];
  const float* b1  = (const float*)d_in[6];
  const float* g1  = (const float*)d_in[7];
  const float* be1 = (const float*)d_in[8];
  const float* m1  = (const float*)d_in[9];
  const float* v1  = (const float*)d_in[10];
  const float* Wl2 = (const float*)d_in[11];
  const float* bl2 = (const float*)d_in[12];
  const float* Wr2 = (const float*)d_in[13];
  const float* g2  = (const float*)d_in[14];
  const float* be2 = (const float*)d_in[15];
  const float* m2  = (const float*)d_in[16];
  const float* v2  = (const float*)d_in[17];
  const float* Wl3 = (const float*)d_in[18];
  const float* bl3 = (const float*)d_in[19];
  const float* Wr3 = (const float*)d_in[20];
  const float* g3  = (const float*)d_in[21];
  const float* be3 = (const float*)d_in[22];
  const float* m3  = (const float*)d_in[23];
  const float* v3  = (const float*)d_in[24];
  const float* W4  = (const float*)d_in[25];
  const float* b4  = (const float*)d_in[26];
  const float* W5  = (const float*)d_in[27];
  const float* b5  = (const float*)d_in[28];

  char* ws = (char*)d_ws;
  size_t off = 0;
  auto alloc = [&](size_t bytes) -> void* {
    void* p = (void*)(ws + off);
    off += (bytes + 255) & ~(size_t)255;
    return p;
  };
  int* gcur    = (int*)alloc(3 * KB * sizeof(int));
  int* rowbeg3 = (int*)alloc(3 * NN * sizeof(int));
  int* deg3    = (int*)alloc(3 * NN * sizeof(int));
  int2* recDS  = (int2*)alloc((size_t)KB * RCAP * 8);
  int* adjI    = (int*)alloc((size_t)KB * RCAP * 4);      // int adj (all layers)
  float* aggE  = (float*)alloc((size_t)NN * 32 * 4);      // ea scatter-sum accumulator
  unsigned short* hbuf = (unsigned short*)alloc((size_t)4 * NN * 128 * 2); // h1/aggH/h2/h3
  unsigned short* agg1 = (unsigned short*)alloc((size_t)NN * 96 * 2);
  unsigned short* xb   = (unsigned short*)alloc((size_t)NN * 64 * 2);
  unsigned short* W1b  = (unsigned short*)alloc(12288 * 2);
  unsigned short* Wl2b = (unsigned short*)alloc(16384 * 2);
  unsigned short* Wr2b = (unsigned short*)alloc(16384 * 2);
  unsigned short* Wl3b = (unsigned short*)alloc(16384 * 2);
  unsigned short* Wr3b = (unsigned short*)alloc(16384 * 2);
  unsigned short* W4b  = (unsigned short*)alloc(12288 * 2);

  unsigned short* h1   = hbuf;
  unsigned short* aggH = h1 + (size_t)NN * 128;
  unsigned short* h2   = h1 + (size_t)2 * NN * 128;
  unsigned short* h3   = h1 + (size_t)3 * NN * 128;

  int* rb0 = rowbeg3;            int* dg0 = deg3;
  int* rb1 = rowbeg3 + NN;       int* dg1 = deg3 + NN;
  int* rb2 = rowbeg3 + 2 * NN;   int* dg2 = deg3 + 2 * NN;

  const int gP2   = (NE + PT2 - 1) / PT2;      // 391
  const int gSum  = (NE * 8) / 256;            // 25000
  const int gAgg  = (NN * 64) / 256;           // 12500
  const int gTile = (3125 * 8 * 64) / 256;     // 6250
  const int gRead = (3125 * 64 + 255) / 256;   // 782
  const int gCvt  = (CVT_END + 255) / 256;

  k_cvt_all<<<gCvt, 256, 0, stream>>>(x, W1, Wl2, Wr2, Wl3, Wr3, W4,
                                      xb, W1b, Wl2b, Wr2b, Wl3b, Wr3b, W4b, gcur, aggE);

  // ---- layer 1 (conv1): streaming ea scatter-sum + x-only CSR gather ----
  k_sumEA<<<gSum, 256, 0, stream>>>(ei0, ea, aggE);
  k_part<<<gP2, 256, 0, stream>>>(ei0, gcur, recDS);
  k_build<<<KB, 256, 0, stream>>>(recDS, gcur, adjI, rb0, dg0);
  k_aggXE<<<gAgg, 256, 0, stream>>>(rb0, dg0, adjI, xb, aggE, agg1);
  k_lin1<<<gTile, 256, 0, stream>>>(agg1, W1b, b1, g1, be1, m1, v1, dg0, h1);

  // ---- layer 2 (SAGE) ----
  k_part<<<gP2, 256, 0, stream>>>(ei1, gcur + KB, recDS);
  k_build<<<KB, 256, 0, stream>>>(recDS, gcur + KB, adjI, rb1, dg1);
  k_aggH<<<gAgg, 256, 0, stream>>>(rb1, dg1, adjI, h1, aggH);
  k_sage<<<gTile, 256, 0, stream>>>(aggH, h1, Wl2b, bl2, Wr2b, g2, be2, m2, v2, h2);

  // ---- layer 3 (SAGE) ----
  k_part<<<gP2, 256, 0, stream>>>(ei2, gcur + 2 * KB, recDS);
  k_build<<<KB, 256, 0, stream>>>(recDS, gcur + 2 * KB, adjI, rb2, dg2);
  k_aggH<<<gAgg, 256, 0, stream>>>(rb2, dg2, adjI, h2, aggH);
  k_sage<<<gTile, 256, 0, stream>>>(aggH, h2, Wl3b, bl3, Wr3b, g3, be3, m3, v3, h3);

  // ---- readout ----
  k_readout<<<gRead, 256, 0, stream>>>(h3, xb, W4b, b4, W5, b5, (float*)d_out);

  (void)in_sizes; (void)n_in; (void)out_size; (void)ws_size;
}

// Round 6
// 579.292 us; speedup vs baseline: 1.3929x; 1.3929x over previous
//
#include <hip/hip_runtime.h>
#include <hip/hip_bf16.h>
#include <stdint.h>

#define NN 50000
#define NE 800000
#define EPS 1e-5f
#define DEGCAP 48    // per-node adjacency capacity (mean deg 16, +8 sigma)

typedef __attribute__((ext_vector_type(8))) short bf16x8;
typedef __attribute__((ext_vector_type(4))) float floatx4;

static __device__ __forceinline__ float bf2f(unsigned int u){
  union { unsigned int i; float f; } c; c.i = u << 16; return c.f;
}
static __device__ __forceinline__ unsigned short f2bf(float f){
  union { float f; unsigned int i; } c; c.f = f;
  unsigned int x = c.i;
  return (unsigned short)((x + 0x7fffu + ((x >> 16) & 1u)) >> 16);
}

// fused f32 -> bf16 converter for x + the 6 GEMM weight matrices;
// also zeros the 3 per-layer degree counters
#define CVT_X   3200000
#define CVT_W1  3212288
#define CVT_WL2 3228672
#define CVT_WR2 3245056
#define CVT_WL3 3261440
#define CVT_WR3 3277824
#define CVT_END 3290112
__global__ void k_cvt_all(const float* __restrict__ x,  const float* __restrict__ W1,
                          const float* __restrict__ Wl2, const float* __restrict__ Wr2,
                          const float* __restrict__ Wl3, const float* __restrict__ Wr3,
                          const float* __restrict__ W4,
                          unsigned short* __restrict__ xb,  unsigned short* __restrict__ W1b,
                          unsigned short* __restrict__ Wl2b, unsigned short* __restrict__ Wr2b,
                          unsigned short* __restrict__ Wl3b, unsigned short* __restrict__ Wr3b,
                          unsigned short* __restrict__ W4b, int* __restrict__ cnt3){
  int i = blockIdx.x * 256 + threadIdx.x;
  if(i >= CVT_END) return;
  if(i < 3 * NN) cnt3[i] = 0;
  if(i < CVT_X)        xb[i] = f2bf(x[i]);
  else if(i < CVT_W1)  W1b[i - CVT_X]    = f2bf(W1[i - CVT_X]);
  else if(i < CVT_WL2) Wl2b[i - CVT_W1]  = f2bf(Wl2[i - CVT_W1]);
  else if(i < CVT_WR2) Wr2b[i - CVT_WL2] = f2bf(Wr2[i - CVT_WL2]);
  else if(i < CVT_WL3) Wl3b[i - CVT_WR2] = f2bf(Wl3[i - CVT_WR2]);
  else if(i < CVT_WR3) Wr3b[i - CVT_WL3] = f2bf(Wr3[i - CVT_WL3]);
  else                 W4b[i - CVT_WR3]  = f2bf(W4[i - CVT_WR3]);
}

// ---- atomic-scatter CSR build, L0 variant: adj[dst*DEGCAP+pos] = {src, eid}.
// Replaces k_part+k_build (bucket staging, LDS scans, 2 atomic rounds, ~50us/layer)
// with one 800K-atomic scatter. Row order is arbitrary (sum is commutative). ----
__global__ void k_scat0(const int* __restrict__ ei, int* __restrict__ cnt,
                        int2* __restrict__ adj){
  int e = blockIdx.x * 256 + threadIdx.x;
  if(e >= NE) return;
  int src = ei[e], dst = ei[NE + e];
  int pos = atomicAdd(&cnt[dst], 1);
  if(pos < DEGCAP) adj[dst * DEGCAP + pos] = make_int2(src, e);
}

// ---- atomic-scatter CSR build, L1/L2 variant: int adj ----
__global__ void k_scat(const int* __restrict__ ei, int* __restrict__ cnt,
                       int* __restrict__ adj){
  int e = blockIdx.x * 256 + threadIdx.x;
  if(e >= NE) return;
  int src = ei[e], dst = ei[NE + e];
  int pos = atomicAdd(&cnt[dst], 1);
  if(pos < DEGCAP) adj[dst * DEGCAP + pos] = src;
}

// ---- fused L0 aggregation (R2-proven structure): wave per node; 16 lanes/edge,
// 8 edges/iter. lanes 0-7 gather xb row (16B each, L2-resident), lanes 8-15
// gather ea row directly from f32 input (16B each = full 128B row). ----
__global__ void k_aggXE(const int* __restrict__ cnt,
                        const int2* __restrict__ adj2,
                        const unsigned short* __restrict__ xb, const float* __restrict__ ea,
                        unsigned short* __restrict__ agg){
  int w = (blockIdx.x * blockDim.x + threadIdx.x) >> 6;
  int lane = threadIdx.x & 63;
  if(w >= NN) return;
  int sub = lane >> 4, li = lane & 15;
  int dg = cnt[w]; if(dg > DEGCAP) dg = DEGCAP;
  int r0 = w * DEGCAP, r1 = r0 + dg;
  float acc[8] = {0.f,0.f,0.f,0.f,0.f,0.f,0.f,0.f};
  for(int k = r0; k < r1; k += 8){
    int e0 = k + sub, e1 = k + 4 + sub;
    int i0 = e0 < r1 ? e0 : r1 - 1;
    int i1 = e1 < r1 ? e1 : r1 - 1;
    float m0 = e0 < r1 ? 1.f : 0.f;
    float m1 = e1 < r1 ? 1.f : 0.f;
    int2 a0 = adj2[i0], a1 = adj2[i1];
    if(li < 8){
      uint4 v0 = *(const uint4*)(xb + (size_t)a0.x * 64 + li * 8);
      uint4 v1 = *(const uint4*)(xb + (size_t)a1.x * 64 + li * 8);
      acc[0] += m0 * bf2f(v0.x & 0xffffu); acc[1] += m0 * bf2f(v0.x >> 16);
      acc[2] += m0 * bf2f(v0.y & 0xffffu); acc[3] += m0 * bf2f(v0.y >> 16);
      acc[4] += m0 * bf2f(v0.z & 0xffffu); acc[5] += m0 * bf2f(v0.z >> 16);
      acc[6] += m0 * bf2f(v0.w & 0xffffu); acc[7] += m0 * bf2f(v0.w >> 16);
      acc[0] += m1 * bf2f(v1.x & 0xffffu); acc[1] += m1 * bf2f(v1.x >> 16);
      acc[2] += m1 * bf2f(v1.y & 0xffffu); acc[3] += m1 * bf2f(v1.y >> 16);
      acc[4] += m1 * bf2f(v1.z & 0xffffu); acc[5] += m1 * bf2f(v1.z >> 16);
      acc[6] += m1 * bf2f(v1.w & 0xffffu); acc[7] += m1 * bf2f(v1.w >> 16);
    } else {
      int j = li - 8;
      float4 p0 = *(const float4*)(ea + (size_t)a0.y * 32 + j * 4);
      float4 p1 = *(const float4*)(ea + (size_t)a1.y * 32 + j * 4);
      acc[0] += m0 * p0.x; acc[1] += m0 * p0.y;
      acc[2] += m0 * p0.z; acc[3] += m0 * p0.w;
      acc[0] += m1 * p1.x; acc[1] += m1 * p1.y;
      acc[2] += m1 * p1.z; acc[3] += m1 * p1.w;
    }
  }
  #pragma unroll
  for(int d = 16; d < 64; d <<= 1){
    #pragma unroll
    for(int i = 0; i < 8; i++) acc[i] += __shfl_xor(acc[i], d, 64);
  }
  if(sub == 0){
    float inv = 1.0f / (float)(dg > 0 ? dg : 1);
    if(li < 8){
      unsigned int q0 = (unsigned int)f2bf(acc[0]*inv) | ((unsigned int)f2bf(acc[1]*inv) << 16);
      unsigned int q1 = (unsigned int)f2bf(acc[2]*inv) | ((unsigned int)f2bf(acc[3]*inv) << 16);
      unsigned int q2 = (unsigned int)f2bf(acc[4]*inv) | ((unsigned int)f2bf(acc[5]*inv) << 16);
      unsigned int q3 = (unsigned int)f2bf(acc[6]*inv) | ((unsigned int)f2bf(acc[7]*inv) << 16);
      *(uint4*)(agg + (size_t)w * 96 + li * 8) = make_uint4(q0, q1, q2, q3);
    } else {
      int j = li - 8;
      unsigned int q0 = (unsigned int)f2bf(acc[0]*inv) | ((unsigned int)f2bf(acc[1]*inv) << 16);
      unsigned int q1 = (unsigned int)f2bf(acc[2]*inv) | ((unsigned int)f2bf(acc[3]*inv) << 16);
      *(uint2*)(agg + (size_t)w * 96 + 64 + j * 4) = make_uint2(q0, q1);
    }
  }
}

// ---- h aggregation (R2-proven structure): wave per node; 16 lanes/edge, 8 edges/iter ----
__global__ void k_aggH(const int* __restrict__ cnt,
                       const int* __restrict__ adj,
                       const unsigned short* __restrict__ h, unsigned short* __restrict__ agg){
  int w = (blockIdx.x * blockDim.x + threadIdx.x) >> 6;
  int lane = threadIdx.x & 63;
  if(w >= NN) return;
  int sub = lane >> 4, li = lane & 15;
  int dg = cnt[w]; if(dg > DEGCAP) dg = DEGCAP;
  int r0 = w * DEGCAP, r1 = r0 + dg;
  float acc[8] = {0.f,0.f,0.f,0.f,0.f,0.f,0.f,0.f};
  for(int k = r0; k < r1; k += 8){
    int e0 = k + sub, e1 = k + 4 + sub;
    int i0 = e0 < r1 ? e0 : r1 - 1;
    int i1 = e1 < r1 ? e1 : r1 - 1;
    float m0 = e0 < r1 ? 1.f : 0.f;
    float m1 = e1 < r1 ? 1.f : 0.f;
    int s0 = adj[i0], s1 = adj[i1];
    uint4 v0 = *(const uint4*)(h + (size_t)s0 * 128 + li * 8);
    uint4 v1 = *(const uint4*)(h + (size_t)s1 * 128 + li * 8);
    acc[0] += m0 * bf2f(v0.x & 0xffffu); acc[1] += m0 * bf2f(v0.x >> 16);
    acc[2] += m0 * bf2f(v0.y & 0xffffu); acc[3] += m0 * bf2f(v0.y >> 16);
    acc[4] += m0 * bf2f(v0.z & 0xffffu); acc[5] += m0 * bf2f(v0.z >> 16);
    acc[6] += m0 * bf2f(v0.w & 0xffffu); acc[7] += m0 * bf2f(v0.w >> 16);
    acc[0] += m1 * bf2f(v1.x & 0xffffu); acc[1] += m1 * bf2f(v1.x >> 16);
    acc[2] += m1 * bf2f(v1.y & 0xffffu); acc[3] += m1 * bf2f(v1.y >> 16);
    acc[4] += m1 * bf2f(v1.z & 0xffffu); acc[5] += m1 * bf2f(v1.z >> 16);
    acc[6] += m1 * bf2f(v1.w & 0xffffu); acc[7] += m1 * bf2f(v1.w >> 16);
  }
  #pragma unroll
  for(int d = 16; d < 64; d <<= 1){
    #pragma unroll
    for(int i = 0; i < 8; i++) acc[i] += __shfl_xor(acc[i], d, 64);
  }
  if(sub == 0){
    float inv = 1.0f / (float)(dg > 0 ? dg : 1);
    unsigned int p0 = (unsigned int)f2bf(acc[0]*inv) | ((unsigned int)f2bf(acc[1]*inv) << 16);
    unsigned int p1 = (unsigned int)f2bf(acc[2]*inv) | ((unsigned int)f2bf(acc[3]*inv) << 16);
    unsigned int p2 = (unsigned int)f2bf(acc[4]*inv) | ((unsigned int)f2bf(acc[5]*inv) << 16);
    unsigned int p3 = (unsigned int)f2bf(acc[6]*inv) | ((unsigned int)f2bf(acc[7]*inv) << 16);
    *(uint4*)(agg + (size_t)w * 128 + li * 8) = make_uint4(p0, p1, p2, p3);
  }
}

// conv1 dense part: h1 = relu(bn(relu(mask_deg(agg @ W1^T + b1))))
__global__ void k_lin1(const unsigned short* __restrict__ agg, const unsigned short* __restrict__ W1,
                       const float* __restrict__ b1,
                       const float* __restrict__ g1, const float* __restrict__ be1,
                       const float* __restrict__ m1, const float* __restrict__ v1,
                       const int* __restrict__ deg, unsigned short* __restrict__ h1){
  int wave = (blockIdx.x * blockDim.x + threadIdx.x) >> 6;
  int lane = threadIdx.x & 63;
  int mt = wave >> 3, nt = wave & 7;
  if(mt >= 3125) return;
  int node0 = mt * 16;
  int col = lane & 15, quad = lane >> 4;
  int o = nt * 16 + col;
  int arow = node0 + col;
  floatx4 acc = {0.f, 0.f, 0.f, 0.f};
  #pragma unroll
  for(int kc = 0; kc < 3; kc++){
    bf16x8 a = *(const bf16x8*)(agg + arow * 96 + kc * 32 + quad * 8);
    bf16x8 b = *(const bf16x8*)(W1 + o * 96 + kc * 32 + quad * 8);
    acc = __builtin_amdgcn_mfma_f32_16x16x32_bf16(a, b, acc, 0, 0, 0);
  }
  float bb = b1[o];
  float sc = g1[o] * rsqrtf(v1[o] + EPS);
  float mv = m1[o], bev = be1[o];
  #pragma unroll
  for(int r = 0; r < 4; r++){
    int node = node0 + quad * 4 + r;
    float pre = (deg[node] > 0) ? (acc[r] + bb) : 0.0f;   // ref: empty segment -> mean 0, bias never added
    float t = fmaxf(pre, 0.f);
    float bn = sc * (t - mv) + bev;
    h1[node * 128 + o] = f2bf(fmaxf(bn, 0.f));
  }
}

// SAGE: hout = relu(bn(agg @ Wl^T + bl + hin @ Wr^T))
__global__ void k_sage(const unsigned short* __restrict__ agg, const unsigned short* __restrict__ hin,
                       const unsigned short* __restrict__ Wl, const float* __restrict__ bl,
                       const unsigned short* __restrict__ Wr,
                       const float* __restrict__ g, const float* __restrict__ be,
                       const float* __restrict__ m, const float* __restrict__ v,
                       unsigned short* __restrict__ hout){
  int wave = (blockIdx.x * blockDim.x + threadIdx.x) >> 6;
  int lane = threadIdx.x & 63;
  int mt = wave >> 3, nt = wave & 7;
  if(mt >= 3125) return;
  int node0 = mt * 16;
  int col = lane & 15, quad = lane >> 4;
  int o = nt * 16 + col;
  int arow = node0 + col;
  floatx4 acc = {0.f, 0.f, 0.f, 0.f};
  #pragma unroll
  for(int kc = 0; kc < 4; kc++){
    bf16x8 a = *(const bf16x8*)(agg + arow * 128 + kc * 32 + quad * 8);
    bf16x8 b = *(const bf16x8*)(Wl + o * 128 + kc * 32 + quad * 8);
    acc = __builtin_amdgcn_mfma_f32_16x16x32_bf16(a, b, acc, 0, 0, 0);
  }
  #pragma unroll
  for(int kc = 0; kc < 4; kc++){
    bf16x8 a = *(const bf16x8*)(hin + arow * 128 + kc * 32 + quad * 8);
    bf16x8 b = *(const bf16x8*)(Wr + o * 128 + kc * 32 + quad * 8);
    acc = __builtin_amdgcn_mfma_f32_16x16x32_bf16(a, b, acc, 0, 0, 0);
  }
  float blv = bl[o];
  float sc = g[o] * rsqrtf(v[o] + EPS);
  float mv = m[o], bev = be[o];
  #pragma unroll
  for(int r = 0; r < 4; r++){
    int node = node0 + quad * 4 + r;
    float pre = acc[r] + blv;
    float bn = sc * (pre - mv) + bev;
    hout[node * 128 + o] = f2bf(fmaxf(bn, 0.f));
  }
}

// readout: z = relu([h3 | x] @ W4^T + b4) (64), out = z @ W5^T + b5  (f32 out)
__global__ void k_readout(const unsigned short* __restrict__ h3, const unsigned short* __restrict__ xb,
                          const unsigned short* __restrict__ W4, const float* __restrict__ b4,
                          const float* __restrict__ W5, const float* __restrict__ b5,
                          float* __restrict__ out){
  int wave = (blockIdx.x * blockDim.x + threadIdx.x) >> 6;
  int lane = threadIdx.x & 63;
  if(wave >= 3125) return;
  int node0 = wave * 16;
  int col = lane & 15, quad = lane >> 4;
  int arow = node0 + col;
  float partial[4] = {0.f, 0.f, 0.f, 0.f};
  #pragma unroll
  for(int nt = 0; nt < 4; nt++){
    int o = nt * 16 + col;
    floatx4 acc = {0.f, 0.f, 0.f, 0.f};
    #pragma unroll
    for(int kc = 0; kc < 4; kc++){
      bf16x8 a = *(const bf16x8*)(h3 + arow * 128 + kc * 32 + quad * 8);
      bf16x8 b = *(const bf16x8*)(W4 + o * 192 + kc * 32 + quad * 8);
      acc = __builtin_amdgcn_mfma_f32_16x16x32_bf16(a, b, acc, 0, 0, 0);
    }
    #pragma unroll
    for(int kc = 0; kc < 2; kc++){
      bf16x8 a = *(const bf16x8*)(xb + arow * 64 + kc * 32 + quad * 8);
      bf16x8 b = *(const bf16x8*)(W4 + o * 192 + 128 + kc * 32 + quad * 8);
      acc = __builtin_amdgcn_mfma_f32_16x16x32_bf16(a, b, acc, 0, 0, 0);
    }
    float bb = b4[o];
    float w5 = W5[o];
    #pragma unroll
    for(int r = 0; r < 4; r++)
      partial[r] += fmaxf(acc[r] + bb, 0.f) * w5;
  }
  #pragma unroll
  for(int d = 1; d < 16; d <<= 1){
    #pragma unroll
    for(int r = 0; r < 4; r++)
      partial[r] += __shfl_xor(partial[r], d, 64);
  }
  if(col == 0){
    float b5f = b5[0];
    #pragma unroll
    for(int r = 0; r < 4; r++)
      out[node0 + quad * 4 + r] = partial[r] + b5f;
  }
}

extern "C" void kernel_launch(void* const* d_in, const int* in_sizes, int n_in,
                              void* d_out, int out_size, void* d_ws, size_t ws_size,
                              hipStream_t stream) {
  const float* x   = (const float*)d_in[0];
  const int* ei0   = (const int*)d_in[1];
  const int* ei1   = (const int*)d_in[2];
  const int* ei2   = (const int*)d_in[3];
  const float* ea  = (const float*)d_in[4];
  const float* W1  = (const float*)d_in[5];
  const float* b1  = (const float*)d_in[6];
  const float* g1  = (const float*)d_in[7];
  const float* be1 = (const float*)d_in[8];
  const float* m1  = (const float*)d_in[9];
  const float* v1  = (const float*)d_in[10];
  const float* Wl2 = (const float*)d_in[11];
  const float* bl2 = (const float*)d_in[12];
  const float* Wr2 = (const float*)d_in[13];
  const float* g2  = (const float*)d_in[14];
  const float* be2 = (const float*)d_in[15];
  const float* m2  = (const float*)d_in[16];
  const float* v2  = (const float*)d_in[17];
  const float* Wl3 = (const float*)d_in[18];
  const float* bl3 = (const float*)d_in[19];
  const float* Wr3 = (const float*)d_in[20];
  const float* g3  = (const float*)d_in[21];
  const float* be3 = (const float*)d_in[22];
  const float* m3  = (const float*)d_in[23];
  const float* v3  = (const float*)d_in[24];
  const float* W4  = (const float*)d_in[25];
  const float* b4  = (const float*)d_in[26];
  const float* W5  = (const float*)d_in[27];
  const float* b5  = (const float*)d_in[28];

  char* ws = (char*)d_ws;
  size_t off = 0;
  auto alloc = [&](size_t bytes) -> void* {
    void* p = (void*)(ws + off);
    off += (bytes + 255) & ~(size_t)255;
    return p;
  };
  int* cnt3    = (int*)alloc(3 * NN * sizeof(int));
  int2* adjB   = (int2*)alloc((size_t)NN * DEGCAP * 8);   // L0: int2 {src,eid}; L1/L2 reuse as int
  unsigned short* hbuf = (unsigned short*)alloc((size_t)3 * NN * 128 * 2); // h1/aggH/h2 slots (h3 -> h1 slot)
  unsigned short* agg1 = (unsigned short*)alloc((size_t)NN * 96 * 2);
  unsigned short* xb   = (unsigned short*)alloc((size_t)NN * 64 * 2);
  unsigned short* W1b  = (unsigned short*)alloc(12288 * 2);
  unsigned short* Wl2b = (unsigned short*)alloc(16384 * 2);
  unsigned short* Wr2b = (unsigned short*)alloc(16384 * 2);
  unsigned short* Wl3b = (unsigned short*)alloc(16384 * 2);
  unsigned short* Wr3b = (unsigned short*)alloc(16384 * 2);
  unsigned short* W4b  = (unsigned short*)alloc(12288 * 2);

  int* adjI = (int*)adjB;   // L1/L2 int adjacency, aliases adjB (dead after k_aggXE / prev aggH)

  // h slots: h1 dead after sage-L2; h3 reuses its slot
  unsigned short* h1   = hbuf;
  unsigned short* aggH = hbuf + (size_t)NN * 128;
  unsigned short* h2   = hbuf + (size_t)2 * NN * 128;
  unsigned short* h3   = h1;

  int* cnt0 = cnt3;
  int* cnt1 = cnt3 + NN;
  int* cnt2 = cnt3 + 2 * NN;

  const int gScat = (NE + 255) / 256;          // 3125
  const int gAgg  = (NN * 64) / 256;           // 12500
  const int gTile = (3125 * 8 * 64) / 256;     // 6250
  const int gRead = (3125 * 64 + 255) / 256;   // 782
  const int gCvt  = (CVT_END + 255) / 256;

  k_cvt_all<<<gCvt, 256, 0, stream>>>(x, W1, Wl2, Wr2, Wl3, Wr3, W4,
                                      xb, W1b, Wl2b, Wr2b, Wl3b, Wr3b, W4b, cnt3);

  // ---- layer 1 (conv1): atomic-scatter CSR + fused x/ea gather ----
  k_scat0<<<gScat, 256, 0, stream>>>(ei0, cnt0, adjB);
  k_aggXE<<<gAgg, 256, 0, stream>>>(cnt0, adjB, xb, ea, agg1);
  k_lin1<<<gTile, 256, 0, stream>>>(agg1, W1b, b1, g1, be1, m1, v1, cnt0, h1);

  // ---- layer 2 (SAGE) ----
  k_scat<<<gScat, 256, 0, stream>>>(ei1, cnt1, adjI);
  k_aggH<<<gAgg, 256, 0, stream>>>(cnt1, adjI, h1, aggH);
  k_sage<<<gTile, 256, 0, stream>>>(aggH, h1, Wl2b, bl2, Wr2b, g2, be2, m2, v2, h2);

  // ---- layer 3 (SAGE) ----
  k_scat<<<gScat, 256, 0, stream>>>(ei2, cnt2, adjI);
  k_aggH<<<gAgg, 256, 0, stream>>>(cnt2, adjI, h2, aggH);
  k_sage<<<gTile, 256, 0, stream>>>(aggH, h2, Wl3b, bl3, Wr3b, g3, be3, m3, v3, h3);

  // ---- readout ----
  k_readout<<<gRead, 256, 0, stream>>>(h3, xb, W4b, b4, W5, b5, (float*)d_out);

  (void)in_sizes; (void)n_in; (void)out_size; (void)ws_size;
}

// Round 7
// 491.323 us; speedup vs baseline: 1.6424x; 1.1790x over previous
//
#include <hip/hip_runtime.h>
#include <hip/hip_bf16.h>
#include <stdint.h>

#define NN 50000
#define NE 800000
#define EPS 1e-5f

// CSR bucket params
#define KB 196       // buckets = ceil(NN / NPB)
#define SH 8         // bucket = dst >> SH
#define NPB 256      // nodes per bucket
#define RCAP 4500    // slots per bucket (mean 4082, +6.6 sigma)
#define PT2 2048     // edges per DS-partition block
#define NT2 391      // tiles per layer = ceil(NE/PT2)

typedef __attribute__((ext_vector_type(8))) short bf16x8;
typedef __attribute__((ext_vector_type(4))) float floatx4;

static __device__ __forceinline__ float bf2f(unsigned int u){
  union { unsigned int i; float f; } c; c.i = u << 16; return c.f;
}
static __device__ __forceinline__ unsigned short f2bf(float f){
  union { float f; unsigned int i; } c; c.f = f;
  unsigned int x = c.i;
  return (unsigned short)((x + 0x7fffu + ((x >> 16) & 1u)) >> 16);
}

// fused f32 -> bf16 converter for x + the 6 GEMM weight matrices; also zeros bucket cursors
#define CVT_X   3200000
#define CVT_W1  3212288
#define CVT_WL2 3228672
#define CVT_WR2 3245056
#define CVT_WL3 3261440
#define CVT_WR3 3277824
#define CVT_END 3290112
__global__ void k_cvt_all(const float* __restrict__ x,  const float* __restrict__ W1,
                          const float* __restrict__ Wl2, const float* __restrict__ Wr2,
                          const float* __restrict__ Wl3, const float* __restrict__ Wr3,
                          const float* __restrict__ W4,
                          unsigned short* __restrict__ xb,  unsigned short* __restrict__ W1b,
                          unsigned short* __restrict__ Wl2b, unsigned short* __restrict__ Wr2b,
                          unsigned short* __restrict__ Wl3b, unsigned short* __restrict__ Wr3b,
                          unsigned short* __restrict__ W4b, int* __restrict__ gcur){
  int i = blockIdx.x * 256 + threadIdx.x;
  if(i >= CVT_END) return;
  if(i < 3 * KB) gcur[i] = 0;
  if(i < CVT_X)        xb[i] = f2bf(x[i]);
  else if(i < CVT_W1)  W1b[i - CVT_X]    = f2bf(W1[i - CVT_X]);
  else if(i < CVT_WL2) Wl2b[i - CVT_W1]  = f2bf(Wl2[i - CVT_W1]);
  else if(i < CVT_WR2) Wr2b[i - CVT_WL2] = f2bf(Wr2[i - CVT_WL2]);
  else if(i < CVT_WL3) Wl3b[i - CVT_WR2] = f2bf(Wl3[i - CVT_WR2]);
  else if(i < CVT_WR3) Wr3b[i - CVT_WL3] = f2bf(Wr3[i - CVT_WL3]);
  else                 W4b[i - CVT_WR3]  = f2bf(W4[i - CVT_WR3]);
}

// ---- FUSED 3-layer partition: one dispatch, 3x391 blocks (layer = blockIdx%3).
// The three per-layer partitions are independent; serial launches left the GPU
// underfilled (391 blocks each). Layer 0 additionally records edge ids (recE). ----
__global__ void k_part3(const int* __restrict__ ei0, const int* __restrict__ ei1,
                        const int* __restrict__ ei2, int* __restrict__ gcur,
                        int2* __restrict__ rec, int* __restrict__ recE){
  __shared__ int2 stage[PT2];
  __shared__ int stE[PT2];
  __shared__ int hist[KB], ex[KB], cur[KB], gbase[KB];
  __shared__ int part[256];
  __shared__ int tot;
  int layer = blockIdx.x % 3;
  int tile = (blockIdx.x / 3) * PT2;
  const int* ei = (layer == 0) ? ei0 : ((layer == 1) ? ei1 : ei2);
  int2* recL = rec + (size_t)layer * KB * RCAP;
  int* gcurL = gcur + layer * KB;
  int tid = threadIdx.x;
  for(int i = tid; i < KB; i += 256) hist[i] = 0;
  __syncthreads();
  int dst[8], src[8];
  #pragma unroll
  for(int j = 0; j < 8; j++){
    int e = tile + j * 256 + tid;
    if(e < NE){ src[j] = ei[e]; dst[j] = ei[NE + e]; atomicAdd(&hist[dst[j] >> SH], 1); }
    else dst[j] = -1;
  }
  __syncthreads();
  int c0 = (tid < KB) ? hist[tid] : 0;
  part[tid] = c0;
  __syncthreads();
  for(int d = 1; d < 256; d <<= 1){
    int v = (tid >= d) ? part[tid - d] : 0;
    __syncthreads();
    part[tid] += v;
    __syncthreads();
  }
  if(tid < KB){
    int e = part[tid] - c0;
    ex[tid] = e; cur[tid] = e;
    gbase[tid] = atomicAdd(&gcurL[tid], c0);
  }
  if(tid == 255) tot = part[255];
  __syncthreads();
  #pragma unroll
  for(int j = 0; j < 8; j++){
    if(dst[j] >= 0){
      int b = dst[j] >> SH;
      int s = atomicAdd(&cur[b], 1);
      stage[s] = make_int2(dst[j], src[j]);
      if(layer == 0) stE[s] = tile + j * 256 + tid;
    }
  }
  __syncthreads();
  for(int s = tid; s < tot; s += 256){
    int2 r = stage[s];
    int b = r.x >> SH;
    int idx = b * RCAP + gbase[b] + (s - ex[b]);
    recL[idx] = r;
    if(layer == 0) recE[idx] = stE[s];
  }
}

// ---- FUSED 3-layer per-bucket CSR build: 3x196 blocks (196 alone badly underfills).
// L0 -> adj2 {src, eid}; L1 -> adjI1; L2 -> adjI2. ----
__global__ void k_build3(const int2* __restrict__ rec, const int* __restrict__ recE,
                         const int* __restrict__ gcnt,
                         int2* __restrict__ adj2, int* __restrict__ adjI1, int* __restrict__ adjI2,
                         int* __restrict__ rowbeg3, int* __restrict__ deg3){
  __shared__ int cnt[NPB], cur2[NPB];
  __shared__ int part[256];
  int layer = blockIdx.x % 3;
  int b = blockIdx.x / 3;
  int tid = threadIdx.x;
  int n0 = b << SH;
  int nr = gcnt[layer * KB + b];
  const int2* r = rec + ((size_t)layer * KB + b) * RCAP;
  const int* re = recE + (size_t)b * RCAP;   // valid only for layer 0
  cnt[tid] = 0;
  __syncthreads();
  for(int k = tid; k < nr; k += 256) atomicAdd(&cnt[r[k].x - n0], 1);
  __syncthreads();
  int c0 = cnt[tid];
  part[tid] = c0;
  __syncthreads();
  for(int d = 1; d < 256; d <<= 1){
    int v = (tid >= d) ? part[tid - d] : 0;
    __syncthreads();
    part[tid] += v;
    __syncthreads();
  }
  int base = part[tid] - c0;
  cur2[tid] = base;
  __syncthreads();
  int n = n0 + tid;
  if(n < NN){ rowbeg3[layer * NN + n] = b * RCAP + base; deg3[layer * NN + n] = c0; }
  for(int k = tid; k < nr; k += 256){
    int2 q = r[k];
    int p = atomicAdd(&cur2[q.x - n0], 1);
    if(layer == 0)      adj2[b * RCAP + p]  = make_int2(q.y, re[k]);
    else if(layer == 1) adjI1[b * RCAP + p] = q.y;
    else                adjI2[b * RCAP + p] = q.y;
  }
}

// ---- fused L0 aggregation (R2-proven): wave per node; 16 lanes/edge, 8 edges/iter.
// lanes 0-7 gather xb row (16B each), lanes 8-15 gather ea row directly (16B each). ----
__global__ void k_aggXE(const int* __restrict__ rowbeg, const int* __restrict__ deg,
                        const int2* __restrict__ adj2,
                        const unsigned short* __restrict__ xb, const float* __restrict__ ea,
                        unsigned short* __restrict__ agg){
  int w = (blockIdx.x * blockDim.x + threadIdx.x) >> 6;
  int lane = threadIdx.x & 63;
  if(w >= NN) return;
  int sub = lane >> 4, li = lane & 15;
  int r0 = rowbeg[w], dg = deg[w], r1 = r0 + dg;
  float acc[8] = {0.f,0.f,0.f,0.f,0.f,0.f,0.f,0.f};
  for(int k = r0; k < r1; k += 8){
    int e0 = k + sub, e1 = k + 4 + sub;
    int i0 = e0 < r1 ? e0 : r1 - 1;
    int i1 = e1 < r1 ? e1 : r1 - 1;
    float m0 = e0 < r1 ? 1.f : 0.f;
    float m1 = e1 < r1 ? 1.f : 0.f;
    int2 a0 = adj2[i0], a1 = adj2[i1];
    if(li < 8){
      uint4 v0 = *(const uint4*)(xb + (size_t)a0.x * 64 + li * 8);
      uint4 v1 = *(const uint4*)(xb + (size_t)a1.x * 64 + li * 8);
      acc[0] += m0 * bf2f(v0.x & 0xffffu); acc[1] += m0 * bf2f(v0.x >> 16);
      acc[2] += m0 * bf2f(v0.y & 0xffffu); acc[3] += m0 * bf2f(v0.y >> 16);
      acc[4] += m0 * bf2f(v0.z & 0xffffu); acc[5] += m0 * bf2f(v0.z >> 16);
      acc[6] += m0 * bf2f(v0.w & 0xffffu); acc[7] += m0 * bf2f(v0.w >> 16);
      acc[0] += m1 * bf2f(v1.x & 0xffffu); acc[1] += m1 * bf2f(v1.x >> 16);
      acc[2] += m1 * bf2f(v1.y & 0xffffu); acc[3] += m1 * bf2f(v1.y >> 16);
      acc[4] += m1 * bf2f(v1.z & 0xffffu); acc[5] += m1 * bf2f(v1.z >> 16);
      acc[6] += m1 * bf2f(v1.w & 0xffffu); acc[7] += m1 * bf2f(v1.w >> 16);
    } else {
      int j = li - 8;
      float4 p0 = *(const float4*)(ea + (size_t)a0.y * 32 + j * 4);
      float4 p1 = *(const float4*)(ea + (size_t)a1.y * 32 + j * 4);
      acc[0] += m0 * p0.x; acc[1] += m0 * p0.y;
      acc[2] += m0 * p0.z; acc[3] += m0 * p0.w;
      acc[0] += m1 * p1.x; acc[1] += m1 * p1.y;
      acc[2] += m1 * p1.z; acc[3] += m1 * p1.w;
    }
  }
  #pragma unroll
  for(int d = 16; d < 64; d <<= 1){
    #pragma unroll
    for(int i = 0; i < 8; i++) acc[i] += __shfl_xor(acc[i], d, 64);
  }
  if(sub == 0){
    float inv = 1.0f / (float)(dg > 0 ? dg : 1);
    if(li < 8){
      unsigned int q0 = (unsigned int)f2bf(acc[0]*inv) | ((unsigned int)f2bf(acc[1]*inv) << 16);
      unsigned int q1 = (unsigned int)f2bf(acc[2]*inv) | ((unsigned int)f2bf(acc[3]*inv) << 16);
      unsigned int q2 = (unsigned int)f2bf(acc[4]*inv) | ((unsigned int)f2bf(acc[5]*inv) << 16);
      unsigned int q3 = (unsigned int)f2bf(acc[6]*inv) | ((unsigned int)f2bf(acc[7]*inv) << 16);
      *(uint4*)(agg + (size_t)w * 96 + li * 8) = make_uint4(q0, q1, q2, q3);
    } else {
      int j = li - 8;
      unsigned int q0 = (unsigned int)f2bf(acc[0]*inv) | ((unsigned int)f2bf(acc[1]*inv) << 16);
      unsigned int q1 = (unsigned int)f2bf(acc[2]*inv) | ((unsigned int)f2bf(acc[3]*inv) << 16);
      *(uint2*)(agg + (size_t)w * 96 + 64 + j * 4) = make_uint2(q0, q1);
    }
  }
}

// ---- h aggregation (R2-proven): wave per node; 16 lanes/edge, 8 edges/iter ----
__global__ void k_aggH(const int* __restrict__ rowbeg, const int* __restrict__ deg,
                       const int* __restrict__ adj,
                       const unsigned short* __restrict__ h, unsigned short* __restrict__ agg){
  int w = (blockIdx.x * blockDim.x + threadIdx.x) >> 6;
  int lane = threadIdx.x & 63;
  if(w >= NN) return;
  int sub = lane >> 4, li = lane & 15;
  int r0 = rowbeg[w], dg = deg[w], r1 = r0 + dg;
  float acc[8] = {0.f,0.f,0.f,0.f,0.f,0.f,0.f,0.f};
  for(int k = r0; k < r1; k += 8){
    int e0 = k + sub, e1 = k + 4 + sub;
    int i0 = e0 < r1 ? e0 : r1 - 1;
    int i1 = e1 < r1 ? e1 : r1 - 1;
    float m0 = e0 < r1 ? 1.f : 0.f;
    float m1 = e1 < r1 ? 1.f : 0.f;
    int s0 = adj[i0], s1 = adj[i1];
    uint4 v0 = *(const uint4*)(h + (size_t)s0 * 128 + li * 8);
    uint4 v1 = *(const uint4*)(h + (size_t)s1 * 128 + li * 8);
    acc[0] += m0 * bf2f(v0.x & 0xffffu); acc[1] += m0 * bf2f(v0.x >> 16);
    acc[2] += m0 * bf2f(v0.y & 0xffffu); acc[3] += m0 * bf2f(v0.y >> 16);
    acc[4] += m0 * bf2f(v0.z & 0xffffu); acc[5] += m0 * bf2f(v0.z >> 16);
    acc[6] += m0 * bf2f(v0.w & 0xffffu); acc[7] += m0 * bf2f(v0.w >> 16);
    acc[0] += m1 * bf2f(v1.x & 0xffffu); acc[1] += m1 * bf2f(v1.x >> 16);
    acc[2] += m1 * bf2f(v1.y & 0xffffu); acc[3] += m1 * bf2f(v1.y >> 16);
    acc[4] += m1 * bf2f(v1.z & 0xffffu); acc[5] += m1 * bf2f(v1.z >> 16);
    acc[6] += m1 * bf2f(v1.w & 0xffffu); acc[7] += m1 * bf2f(v1.w >> 16);
  }
  #pragma unroll
  for(int d = 16; d < 64; d <<= 1){
    #pragma unroll
    for(int i = 0; i < 8; i++) acc[i] += __shfl_xor(acc[i], d, 64);
  }
  if(sub == 0){
    float inv = 1.0f / (float)(dg > 0 ? dg : 1);
    unsigned int p0 = (unsigned int)f2bf(acc[0]*inv) | ((unsigned int)f2bf(acc[1]*inv) << 16);
    unsigned int p1 = (unsigned int)f2bf(acc[2]*inv) | ((unsigned int)f2bf(acc[3]*inv) << 16);
    unsigned int p2 = (unsigned int)f2bf(acc[4]*inv) | ((unsigned int)f2bf(acc[5]*inv) << 16);
    unsigned int p3 = (unsigned int)f2bf(acc[6]*inv) | ((unsigned int)f2bf(acc[7]*inv) << 16);
    *(uint4*)(agg + (size_t)w * 128 + li * 8) = make_uint4(p0, p1, p2, p3);
  }
}

// conv1 dense part: h1 = relu(bn(relu(mask_deg(agg @ W1^T + b1))))
__global__ void k_lin1(const unsigned short* __restrict__ agg, const unsigned short* __restrict__ W1,
                       const float* __restrict__ b1,
                       const float* __restrict__ g1, const float* __restrict__ be1,
                       const float* __restrict__ m1, const float* __restrict__ v1,
                       const int* __restrict__ deg, unsigned short* __restrict__ h1){
  int wave = (blockIdx.x * blockDim.x + threadIdx.x) >> 6;
  int lane = threadIdx.x & 63;
  int mt = wave >> 3, nt = wave & 7;
  if(mt >= 3125) return;
  int node0 = mt * 16;
  int col = lane & 15, quad = lane >> 4;
  int o = nt * 16 + col;
  int arow = node0 + col;
  floatx4 acc = {0.f, 0.f, 0.f, 0.f};
  #pragma unroll
  for(int kc = 0; kc < 3; kc++){
    bf16x8 a = *(const bf16x8*)(agg + arow * 96 + kc * 32 + quad * 8);
    bf16x8 b = *(const bf16x8*)(W1 + o * 96 + kc * 32 + quad * 8);
    acc = __builtin_amdgcn_mfma_f32_16x16x32_bf16(a, b, acc, 0, 0, 0);
  }
  float bb = b1[o];
  float sc = g1[o] * rsqrtf(v1[o] + EPS);
  float mv = m1[o], bev = be1[o];
  #pragma unroll
  for(int r = 0; r < 4; r++){
    int node = node0 + quad * 4 + r;
    float pre = (deg[node] > 0) ? (acc[r] + bb) : 0.0f;   // ref: empty segment -> mean 0, bias never added
    float t = fmaxf(pre, 0.f);
    float bn = sc * (t - mv) + bev;
    h1[node * 128 + o] = f2bf(fmaxf(bn, 0.f));
  }
}

// SAGE: hout = relu(bn(agg @ Wl^T + bl + hin @ Wr^T))
__global__ void k_sage(const unsigned short* __restrict__ agg, const unsigned short* __restrict__ hin,
                       const unsigned short* __restrict__ Wl, const float* __restrict__ bl,
                       const unsigned short* __restrict__ Wr,
                       const float* __restrict__ g, const float* __restrict__ be,
                       const float* __restrict__ m, const float* __restrict__ v,
                       unsigned short* __restrict__ hout){
  int wave = (blockIdx.x * blockDim.x + threadIdx.x) >> 6;
  int lane = threadIdx.x & 63;
  int mt = wave >> 3, nt = wave & 7;
  if(mt >= 3125) return;
  int node0 = mt * 16;
  int col = lane & 15, quad = lane >> 4;
  int o = nt * 16 + col;
  int arow = node0 + col;
  floatx4 acc = {0.f, 0.f, 0.f, 0.f};
  #pragma unroll
  for(int kc = 0; kc < 4; kc++){
    bf16x8 a = *(const bf16x8*)(agg + arow * 128 + kc * 32 + quad * 8);
    bf16x8 b = *(const bf16x8*)(Wl + o * 128 + kc * 32 + quad * 8);
    acc = __builtin_amdgcn_mfma_f32_16x16x32_bf16(a, b, acc, 0, 0, 0);
  }
  #pragma unroll
  for(int kc = 0; kc < 4; kc++){
    bf16x8 a = *(const bf16x8*)(hin + arow * 128 + kc * 32 + quad * 8);
    bf16x8 b = *(const bf16x8*)(Wr + o * 128 + kc * 32 + quad * 8);
    acc = __builtin_amdgcn_mfma_f32_16x16x32_bf16(a, b, acc, 0, 0, 0);
  }
  float blv = bl[o];
  float sc = g[o] * rsqrtf(v[o] + EPS);
  float mv = m[o], bev = be[o];
  #pragma unroll
  for(int r = 0; r < 4; r++){
    int node = node0 + quad * 4 + r;
    float pre = acc[r] + blv;
    float bn = sc * (pre - mv) + bev;
    hout[node * 128 + o] = f2bf(fmaxf(bn, 0.f));
  }
}

// readout: z = relu([h3 | x] @ W4^T + b4) (64), out = z @ W5^T + b5  (f32 out)
__global__ void k_readout(const unsigned short* __restrict__ h3, const unsigned short* __restrict__ xb,
                          const unsigned short* __restrict__ W4, const float* __restrict__ b4,
                          const float* __restrict__ W5, const float* __restrict__ b5,
                          float* __restrict__ out){
  int wave = (blockIdx.x * blockDim.x + threadIdx.x) >> 6;
  int lane = threadIdx.x & 63;
  if(wave >= 3125) return;
  int node0 = wave * 16;
  int col = lane & 15, quad = lane >> 4;
  int arow = node0 + col;
  float partial[4] = {0.f, 0.f, 0.f, 0.f};
  #pragma unroll
  for(int nt = 0; nt < 4; nt++){
    int o = nt * 16 + col;
    floatx4 acc = {0.f, 0.f, 0.f, 0.f};
    #pragma unroll
    for(int kc = 0; kc < 4; kc++){
      bf16x8 a = *(const bf16x8*)(h3 + arow * 128 + kc * 32 + quad * 8);
      bf16x8 b = *(const bf16x8*)(W4 + o * 192 + kc * 32 + quad * 8);
      acc = __builtin_amdgcn_mfma_f32_16x16x32_bf16(a, b, acc, 0, 0, 0);
    }
    #pragma unroll
    for(int kc = 0; kc < 2; kc++){
      bf16x8 a = *(const bf16x8*)(xb + arow * 64 + kc * 32 + quad * 8);
      bf16x8 b = *(const bf16x8*)(W4 + o * 192 + 128 + kc * 32 + quad * 8);
      acc = __builtin_amdgcn_mfma_f32_16x16x32_bf16(a, b, acc, 0, 0, 0);
    }
    float bb = b4[o];
    float w5 = W5[o];
    #pragma unroll
    for(int r = 0; r < 4; r++)
      partial[r] += fmaxf(acc[r] + bb, 0.f) * w5;
  }
  #pragma unroll
  for(int d = 1; d < 16; d <<= 1){
    #pragma unroll
    for(int r = 0; r < 4; r++)
      partial[r] += __shfl_xor(partial[r], d, 64);
  }
  if(col == 0){
    float b5f = b5[0];
    #pragma unroll
    for(int r = 0; r < 4; r++)
      out[node0 + quad * 4 + r] = partial[r] + b5f;
  }
}

extern "C" void kernel_launch(void* const* d_in, const int* in_sizes, int n_in,
                              void* d_out, int out_size, void* d_ws, size_t ws_size,
                              hipStream_t stream) {
  const float* x   = (const float*)d_in[0];
  const int* ei0   = (const int*)d_in[1];
  const int* ei1   = (const int*)d_in[2];
  const int* ei2   = (const int*)d_in[3];
  const float* ea  = (const float*)d_in[4];
  const float* W1  = (const float*)d_in[5];
  const float* b1  = (const float*)d_in[6];
  const float* g1  = (const float*)d_in[7];
  const float* be1 = (const float*)d_in[8];
  const float* m1  = (const float*)d_in[9];
  const float* v1  = (const float*)d_in[10];
  const float* Wl2 = (const float*)d_in[11];
  const float* bl2 = (const float*)d_in[12];
  const float* Wr2 = (const float*)d_in[13];
  const float* g2  = (const float*)d_in[14];
  const float* be2 = (const float*)d_in[15];
  const float* m2  = (const float*)d_in[16];
  const float* v2  = (const float*)d_in[17];
  const float* Wl3 = (const float*)d_in[18];
  const float* bl3 = (const float*)d_in[19];
  const float* Wr3 = (const float*)d_in[20];
  const float* g3  = (const float*)d_in[21];
  const float* be3 = (const float*)d_in[22];
  const float* m3  = (const float*)d_in[23];
  const float* v3  = (const float*)d_in[24];
  const float* W4  = (const float*)d_in[25];
  const float* b4  = (const float*)d_in[26];
  const float* W5  = (const float*)d_in[27];
  const float* b5  = (const float*)d_in[28];

  char* ws = (char*)d_ws;
  size_t off = 0;
  auto alloc = [&](size_t bytes) -> void* {
    void* p = (void*)(ws + off);
    off += (bytes + 255) & ~(size_t)255;
    return p;
  };
  int* gcur    = (int*)alloc(3 * KB * sizeof(int));
  int* rowbeg3 = (int*)alloc(3 * NN * sizeof(int));
  int* deg3    = (int*)alloc(3 * NN * sizeof(int));
  // UNION region: phase 1 = rec(3 layers, 21.2MB) + recE(3.53MB); phase 2 (from
  // k_lin1 on, rec/recE dead after k_build3) = h1/aggH/h2 (38.4MB). size = max.
  char* uni    = (char*)alloc((size_t)3 * NN * 128 * 2);
  int2* adj2   = (int2*)alloc((size_t)KB * RCAP * 8);
  int* adjI1   = (int*)alloc((size_t)KB * RCAP * 4);
  int* adjI2   = (int*)alloc((size_t)KB * RCAP * 4);
  unsigned short* agg1 = (unsigned short*)alloc((size_t)NN * 96 * 2);
  unsigned short* xb   = (unsigned short*)alloc((size_t)NN * 64 * 2);
  unsigned short* W1b  = (unsigned short*)alloc(12288 * 2);
  unsigned short* Wl2b = (unsigned short*)alloc(16384 * 2);
  unsigned short* Wr2b = (unsigned short*)alloc(16384 * 2);
  unsigned short* Wl3b = (unsigned short*)alloc(16384 * 2);
  unsigned short* Wr3b = (unsigned short*)alloc(16384 * 2);
  unsigned short* W4b  = (unsigned short*)alloc(12288 * 2);

  // phase-1 aliases inside uni
  int2* recDS = (int2*)uni;                                     // 3*KB*RCAP int2 = 21.17MB
  int* recE   = (int*)(uni + (((size_t)3 * KB * RCAP * 8 + 255) & ~(size_t)255)); // 3.53MB
  // phase-2 aliases inside uni (h3 reuses h1's slot; proven safe in R6)
  unsigned short* h1   = (unsigned short*)uni;
  unsigned short* aggH = h1 + (size_t)NN * 128;
  unsigned short* h2   = h1 + (size_t)2 * NN * 128;
  unsigned short* h3   = h1;

  int* rb0 = rowbeg3;            int* dg0 = deg3;
  int* rb1 = rowbeg3 + NN;       int* dg1 = deg3 + NN;
  int* rb2 = rowbeg3 + 2 * NN;   int* dg2 = deg3 + 2 * NN;

  const int gP3   = 3 * NT2;                   // 1173
  const int gB3   = 3 * KB;                    // 588
  const int gAgg  = (NN * 64) / 256;           // 12500
  const int gTile = (3125 * 8 * 64) / 256;     // 6250
  const int gRead = (3125 * 64 + 255) / 256;   // 782
  const int gCvt  = (CVT_END + 255) / 256;

  k_cvt_all<<<gCvt, 256, 0, stream>>>(x, W1, Wl2, Wr2, Wl3, Wr3, W4,
                                      xb, W1b, Wl2b, Wr2b, Wl3b, Wr3b, W4b, gcur);

  // ---- fused partition + CSR build for all 3 layers ----
  k_part3<<<gP3, 256, 0, stream>>>(ei0, ei1, ei2, gcur, recDS, recE);
  k_build3<<<gB3, 256, 0, stream>>>(recDS, recE, gcur, adj2, adjI1, adjI2, rowbeg3, deg3);

  // ---- layer 1 (conv1) ----
  k_aggXE<<<gAgg, 256, 0, stream>>>(rb0, dg0, adj2, xb, ea, agg1);
  k_lin1<<<gTile, 256, 0, stream>>>(agg1, W1b, b1, g1, be1, m1, v1, dg0, h1);

  // ---- layer 2 (SAGE) ----
  k_aggH<<<gAgg, 256, 0, stream>>>(rb1, dg1, adjI1, h1, aggH);
  k_sage<<<gTile, 256, 0, stream>>>(aggH, h1, Wl2b, bl2, Wr2b, g2, be2, m2, v2, h2);

  // ---- layer 3 (SAGE) ----
  k_aggH<<<gAgg, 256, 0, stream>>>(rb2, dg2, adjI2, h2, aggH);
  k_sage<<<gTile, 256, 0, stream>>>(aggH, h2, Wl3b, bl3, Wr3b, g3, be3, m3, v3, h3);

  // ---- readout ----
  k_readout<<<gRead, 256, 0, stream>>>(h3, xb, W4b, b4, W5, b5, (float*)d_out);

  (void)in_sizes; (void)n_in; (void)out_size; (void)ws_size;
}